// Round 1
// baseline (462.768 us; speedup 1.0000x reference)
//
#include <hip/hip_runtime.h>

#define BATCH 16
#define CIN   200
#define T1    8192
#define COUTC 400
#define TT2   4096
#define NJ    25
#define NGROUP 10
#define CPG   40
#define NPOOL 14

__constant__ int NBR_OFF[NJ + 1] = {0,8,14,18,21,29,35,39,42,50,56,63,72,80,85,94,101,106,110,113,122,129,134,138,141,145};
__constant__ int NBR[145] = {
 0,1,2,4,5,8,9,24,
 0,1,2,3,4,8,
 0,1,2,3,
 1,2,3,
 0,1,4,5,6,8,9,24,
 0,4,5,6,7,8,
 4,5,6,7,
 5,6,7,
 0,1,4,5,8,9,10,24,
 0,4,8,9,10,11,
 8,9,10,11,12,14,19,
 9,10,11,12,13,14,15,19,20,
 10,11,12,13,14,15,19,20,
 11,12,13,14,19,
 10,11,12,13,14,15,16,19,20,
 11,12,14,15,16,17,19,
 14,15,16,17,18,
 15,16,17,18,
 16,17,18,
 10,11,12,13,14,15,19,20,21,
 11,12,14,19,20,21,22,
 19,20,21,22,23,
 20,21,22,23,
 21,22,23,
 0,4,8,24};
__constant__ int PAIR_A[NPOOL] = {0,2,4,6,8,10,12,14,15,17,19,20,22,24};
__constant__ int PAIR_B[NPOOL] = {1,3,5,7,9,11,13,-1,16,18,-1,21,23,-1};

// ---------------- Kernel A: conv0 (K=3, s=1, reflect pad 1) + PReLU ----------------
// grid (32, 25, 16), block 256.  out h0: (B, 200, 8192)
__global__ __launch_bounds__(256) void conv0_prelu(
    const float* __restrict__ x, const float* __restrict__ w0,
    const float* __restrict__ b0, const float* __restrict__ a0,
    float* __restrict__ h0)
{
    const int jo  = blockIdx.y;
    const int b   = blockIdx.z;
    const int tid = threadIdx.x;
    const int t   = blockIdx.x * 256 + tid;

    const int off  = NBR_OFF[jo];
    const int nci  = (NBR_OFF[jo + 1] - off) * 8;

    __shared__ float wl[72 * 24];   // [cl][k][oc]  (k*8+oc)
    __shared__ int   cil[72];
    __shared__ float bl[8];

    for (int i = tid; i < nci; i += 256)
        cil[i] = NBR[off + (i >> 3)] * 8 + (i & 7);
    const int wtot = nci * 24;
    for (int idx = tid; idx < wtot; idx += 256) {
        int cl = idx / 24;
        int r  = idx - cl * 24;
        int k  = r >> 3;
        int oc = r & 7;
        int ci = NBR[off + (cl >> 3)] * 8 + (cl & 7);
        wl[idx] = w0[(size_t)(jo * 8 + oc) * (CIN * 3) + ci * 3 + k];
    }
    if (tid < 8) bl[tid] = b0[jo * 8 + tid];
    __syncthreads();

    const float alpha = a0[0];
    float acc[8];
#pragma unroll
    for (int oc = 0; oc < 8; ++oc) acc[oc] = bl[oc];

    const int tm1 = (t == 0) ? 1 : t - 1;
    const int tp1 = (t == T1 - 1) ? T1 - 2 : t + 1;
    const float* xb = x + (size_t)b * CIN * T1;

    for (int cl = 0; cl < nci; ++cl) {
        const float* xc = xb + (size_t)cil[cl] * T1;
        float xm = xc[tm1], x0 = xc[t], xp = xc[tp1];
        const float* w = &wl[cl * 24];
#pragma unroll
        for (int oc = 0; oc < 8; ++oc)
            acc[oc] += w[oc] * xm + w[8 + oc] * x0 + w[16 + oc] * xp;
    }

    float* hb = h0 + (size_t)b * CIN * T1 + (size_t)(jo * 8) * T1 + t;
#pragma unroll
    for (int oc = 0; oc < 8; ++oc) {
        float v = acc[oc];
        hb[(size_t)oc * T1] = (v >= 0.f) ? v : alpha * v;
    }
}

// ---------------- Kernel B: conv1 (K=3, s=2, reflect pad 1) ----------------
// grid (16, 25, 16), block 256.  out h1: (B, 400, 4096)
__global__ __launch_bounds__(256) void conv1_k(
    const float* __restrict__ h0, const float* __restrict__ w1,
    const float* __restrict__ b1, float* __restrict__ h1)
{
    const int jo  = blockIdx.y;
    const int b   = blockIdx.z;
    const int tid = threadIdx.x;
    const int t2  = blockIdx.x * 256 + tid;

    const int off = NBR_OFF[jo];
    const int nci = (NBR_OFF[jo + 1] - off) * 8;

    __shared__ float wl[72 * 48];   // [cl][k][oc]  (k*16+oc)  13.8 KB
    __shared__ int   cil[72];
    __shared__ float bl[16];

    for (int i = tid; i < nci; i += 256)
        cil[i] = NBR[off + (i >> 3)] * 8 + (i & 7);
    const int wtot = nci * 48;
    for (int idx = tid; idx < wtot; idx += 256) {
        int cl = idx / 48;
        int r  = idx - cl * 48;
        int k  = r >> 4;
        int oc = r & 15;
        int ci = NBR[off + (cl >> 3)] * 8 + (cl & 7);
        wl[idx] = w1[(size_t)(jo * 16 + oc) * (CIN * 3) + ci * 3 + k];
    }
    if (tid < 16) bl[tid] = b1[jo * 16 + tid];
    __syncthreads();

    float acc[16];
#pragma unroll
    for (int oc = 0; oc < 16; ++oc) acc[oc] = bl[oc];

    const int p0 = (t2 == 0) ? 1 : (2 * t2 - 1);
    const int p1 = 2 * t2;
    const int p2 = 2 * t2 + 1;
    const float* hb = h0 + (size_t)b * CIN * T1;

    for (int cl = 0; cl < nci; ++cl) {
        const float* xc = hb + (size_t)cil[cl] * T1;
        float xm = xc[p0], x0 = xc[p1], xp = xc[p2];
        const float* w = &wl[cl * 48];
#pragma unroll
        for (int oc = 0; oc < 16; ++oc)
            acc[oc] += w[oc] * xm + w[16 + oc] * x0 + w[32 + oc] * xp;
    }

    float* ob = h1 + (size_t)b * COUTC * TT2 + (size_t)(jo * 16) * TT2 + t2;
#pragma unroll
    for (int oc = 0; oc < 16; ++oc)
        ob[(size_t)oc * TT2] = acc[oc];
}

// ---------------- Kernel C: GroupNorm partial sums (deterministic) ----------------
// grid (32, 10, 16), block 256.  part[b][g][slice][2]
__global__ __launch_bounds__(256) void gn_part(
    const float* __restrict__ h1, float* __restrict__ part)
{
    const int sl = blockIdx.x, g = blockIdx.y, b = blockIdx.z;
    const int tid = threadIdx.x;
    const int t0 = sl * (TT2 / 32);   // 128 per slice

    const float* base = h1 + (size_t)b * COUTC * TT2 + (size_t)g * CPG * TT2;
    float s = 0.f, ss = 0.f;
    for (int i = tid; i < CPG * 128; i += 256) {
        int c = i >> 7;
        int t = i & 127;
        float v = base[(size_t)c * TT2 + t0 + t];
        s += v; ss += v * v;
    }
    // wave reduce (64 lanes), then cross-wave via LDS
    for (int o = 32; o; o >>= 1) {
        s  += __shfl_down(s, o, 64);
        ss += __shfl_down(ss, o, 64);
    }
    __shared__ float rs[4], rss[4];
    const int lane = tid & 63, wv = tid >> 6;
    if (lane == 0) { rs[wv] = s; rss[wv] = ss; }
    __syncthreads();
    if (tid == 0) {
        float S = rs[0] + rs[1] + rs[2] + rs[3];
        float SS = rss[0] + rss[1] + rss[2] + rss[3];
        size_t o = (((size_t)b * NGROUP + g) * 32 + sl) * 2;
        part[o] = S;
        part[o + 1] = SS;
    }
}

// ---------------- Kernel D: finalize stats ----------------
__global__ void gn_final(const float* __restrict__ part, float* __restrict__ stats)
{
    int i = threadIdx.x;   // 160 of 256 active: (b,g)
    if (i < BATCH * NGROUP) {
        float s = 0.f, ss = 0.f;
        for (int k = 0; k < 32; ++k) {
            s  += part[((size_t)i * 32 + k) * 2];
            ss += part[((size_t)i * 32 + k) * 2 + 1];
        }
        const float invN = 1.0f / (float)(CPG * TT2);
        float mean = s * invN;
        float var  = ss * invN - mean * mean;
        stats[i * 2]     = mean;
        stats[i * 2 + 1] = rsqrtf(var + 1e-5f);
    }
}

// ---------------- Kernel E: gn + shortcut conv(K=1,s=2) + pool + PReLU ----------------
// grid (16, 14, 16), block 256.  out: (B, 224, 4096)
__global__ __launch_bounds__(256) void final_k(
    const float* __restrict__ x, const float* __restrict__ h1,
    const float* __restrict__ stats, const float* __restrict__ gamma,
    const float* __restrict__ beta, const float* __restrict__ ws,
    const float* __restrict__ bs, const float* __restrict__ a1,
    float* __restrict__ out)
{
    const int n  = blockIdx.y;
    const int b  = blockIdx.z;
    const int tid = threadIdx.x;
    const int t2 = blockIdx.x * 256 + tid;

    int js[2];
    js[0] = PAIR_A[n];
    const int jb = PAIR_B[n];
    const int L = (jb >= 0) ? 2 : 1;
    js[1] = (jb >= 0) ? jb : js[0];

    __shared__ float wsl[2][72 * 16];
    __shared__ int   cill[2][72];
    __shared__ float gl[2][16], btl[2][16], bsl[2][16], ml[2][16], rl[2][16];

    for (int ji = 0; ji < L; ++ji) {
        const int j   = js[ji];
        const int off = NBR_OFF[j];
        const int nci = (NBR_OFF[j + 1] - off) * 8;
        for (int i = tid; i < nci; i += 256)
            cill[ji][i] = NBR[off + (i >> 3)] * 8 + (i & 7);
        for (int idx = tid; idx < nci * 16; idx += 256) {
            int cl = idx >> 4;
            int c  = idx & 15;
            int ci = NBR[off + (cl >> 3)] * 8 + (cl & 7);
            wsl[ji][idx] = ws[(size_t)(j * 16 + c) * CIN + ci];
        }
        if (tid < 16) {
            int ch = j * 16 + tid;
            gl[ji][tid]  = gamma[ch];
            btl[ji][tid] = beta[ch];
            bsl[ji][tid] = bs[ch];
            int g = ch / CPG;
            ml[ji][tid] = stats[((size_t)b * NGROUP + g) * 2];
            rl[ji][tid] = stats[((size_t)b * NGROUP + g) * 2 + 1];
        }
    }
    __syncthreads();

    const float alpha = a1[0];
    const float* xb  = x  + (size_t)b * CIN * T1;
    const float* h1b = h1 + (size_t)b * COUTC * TT2;
    const int p = 2 * t2;

    float acc[16];
#pragma unroll
    for (int c = 0; c < 16; ++c) acc[c] = 0.f;

    for (int ji = 0; ji < L; ++ji) {
        const int j   = js[ji];
        const int nci = (NBR_OFF[j + 1] - NBR_OFF[j]) * 8;
        float sv[16];
#pragma unroll
        for (int c = 0; c < 16; ++c) sv[c] = bsl[ji][c];
        for (int cl = 0; cl < nci; ++cl) {
            float xv = xb[(size_t)cill[ji][cl] * T1 + p];
            const float* wr = &wsl[ji][cl * 16];
#pragma unroll
            for (int c = 0; c < 16; ++c) sv[c] += wr[c] * xv;
        }
#pragma unroll
        for (int c = 0; c < 16; ++c) {
            float hv = h1b[(size_t)(j * 16 + c) * TT2 + t2];
            float gn = (hv - ml[ji][c]) * rl[ji][c] * gl[ji][c] + btl[ji][c];
            acc[c] += gn + sv[c];
        }
    }

    const float invL = 1.0f / (float)L;
    float* ob = out + ((size_t)b * 224 + (size_t)n * 16) * TT2 + t2;
#pragma unroll
    for (int c = 0; c < 16; ++c) {
        float v = acc[c] * invL;
        ob[(size_t)c * TT2] = (v >= 0.f) ? v : alpha * v;
    }
}

extern "C" void kernel_launch(void* const* d_in, const int* in_sizes, int n_in,
                              void* d_out, int out_size, void* d_ws, size_t ws_size,
                              hipStream_t stream) {
    const float* x     = (const float*)d_in[0];
    const float* w0    = (const float*)d_in[1];
    const float* b0    = (const float*)d_in[2];
    const float* a0    = (const float*)d_in[3];
    const float* w1    = (const float*)d_in[4];
    const float* b1    = (const float*)d_in[5];
    const float* gamma = (const float*)d_in[6];
    const float* beta  = (const float*)d_in[7];
    const float* ws    = (const float*)d_in[8];
    const float* bs    = (const float*)d_in[9];
    const float* a1    = (const float*)d_in[10];
    float* out = (float*)d_out;

    float* h0    = (float*)d_ws;                                   // 26,214,400 floats
    float* h1    = h0 + (size_t)BATCH * CIN * T1;                  // 26,214,400 floats
    float* part  = h1 + (size_t)BATCH * COUTC * TT2;               // 10,240 floats
    float* stats = part + (size_t)BATCH * NGROUP * 32 * 2;         // 320 floats

    conv0_prelu<<<dim3(T1 / 256, NJ, BATCH), 256, 0, stream>>>(x, w0, b0, a0, h0);
    conv1_k<<<dim3(TT2 / 256, NJ, BATCH), 256, 0, stream>>>(h0, w1, b1, h1);
    gn_part<<<dim3(32, NGROUP, BATCH), 256, 0, stream>>>(h1, part);
    gn_final<<<1, 256, 0, stream>>>(part, stats);
    final_k<<<dim3(TT2 / 256, NPOOL, BATCH), 256, 0, stream>>>(x, h1, stats, gamma, beta, ws, bs, a1, out);
}